// Round 6
// baseline (148.653 us; speedup 1.0000x reference)
//
#include <hip/hip_runtime.h>
#include <cstdint>

#define BB     4096
#define TT     96
#define NC     85
#define BLANKC 84
#define DD     64
#define ALPHA  0.05f
#define BT     (BB * TT)      // 393216
#define SLICE_F (NC * 17)     // 1445 floats per wave-private slice (pad 16->17)

// ---------------------------------------------------------------------------
// Kernel 1: fused argmax + CTC mask + counts. Block = one batch row (96
// positions): stage 96x85 floats (2040 float4, pure linear copy, coalesced,
// 2-way LDS write = free) -> scan unpadded stride-85 (odd stride: scalar LDS
// reads conflict-free) with thread (r,q) owning a column quarter -> combine
// (strict > over ascending q keeps first-max tie-break) -> mask uses in-block
// pls[t+1] (t=95 needs none) -> labm pack + LDS histogram -> global counts.
// Block 0 zeroes out[0] for k_reduce's atomic accumulation. ~36 KB LDS,
// 4 blocks/CU = 32 waves/CU.
// ---------------------------------------------------------------------------
template<int C0, int C1>
__device__ inline void scanR(const float* __restrict__ row, float& bv, int& bc) {
    bv = row[C0]; bc = C0;
#pragma unroll
    for (int c = C0 + 1; c < C1; ++c) {
        float v = row[c];
        if (v > bv) { bv = v; bc = c; }
    }
}

__global__ __launch_bounds__(512) void k_amask(const float4* __restrict__ p4,
                                               const int* __restrict__ labels,
                                               unsigned* __restrict__ labm,
                                               int* __restrict__ counts,
                                               float* __restrict__ out) {
    __shared__ float rows[TT * NC];                // 8160 floats, stride 85
    __shared__ float sv[4 * TT];
    __shared__ int   sc[4 * TT];
    __shared__ int   pls[TT];
    __shared__ int   h[NC];
    int tid = threadIdx.x;
    int b   = blockIdx.x;
    if (tid < NC) h[tid] = 0;
    if (b == 0 && tid == 256) out[0] = 0.f;

    const float4* src = p4 + (size_t)b * (TT * NC / 4);
    float4* r4 = (float4*)rows;
    for (int i = tid; i < TT * NC / 4; i += 512) r4[i] = src[i];
    __syncthreads();

    int q = tid >> 7, r = tid & 127;               // q wave-uniform
    if (r < TT) {
        const float* row = rows + r * NC;
        float bv; int bc;
        switch (q) {
            case 0:  scanR< 0, 22>(row, bv, bc); break;
            case 1:  scanR<22, 43>(row, bv, bc); break;
            case 2:  scanR<43, 64>(row, bv, bc); break;
            default: scanR<64, 85>(row, bv, bc); break;
        }
        sv[q * TT + r] = bv; sc[q * TT + r] = bc;
    }
    __syncthreads();
    if (tid < TT) {
        float bv = sv[tid]; int bc = sc[tid];
#pragma unroll
        for (int qq = 1; qq < 4; ++qq) {
            float v = sv[qq * TT + tid];
            int   c = sc[qq * TT + tid];
            if (v > bv) { bv = v; bc = c; }        // strict >: lower col wins ties
        }
        pls[tid] = bc;
    }
    __syncthreads();
    if (tid < TT) {
        int p = pls[tid];
        int m = (p != BLANKC) && (tid == TT - 1 || p != pls[tid + 1]);
        int lab = labels[b * TT + tid];
        labm[b * TT + tid] = (unsigned)lab | ((unsigned)m << 31);
        atomicAdd(&h[lab], m);
    }
    __syncthreads();
    if (tid < NC && h[tid]) atomicAdd(&counts[tid], h[tid]);
}

// ---------------------------------------------------------------------------
// Kernel 2: masked feature segment-sum. 8 waves/block; wave w owns dim-quad
// dq=w&3 with a PRIVATE slice [85][17]. Per step: one broadcast uint4 load of
// the 4 packed label words (all lanes, same addr -> L1 broadcast) gives every
// lane all 4 labels: dup check = 6 scalar compares (wave-uniform), own label
// = 2 selects. LDS ops/step: 1 ds_read + 1 ds_write (atomic fallback ~7%).
// ---------------------------------------------------------------------------
__global__ __launch_bounds__(512) void k_main(const float* __restrict__ feat,
                                              const unsigned* __restrict__ labm,
                                              float* __restrict__ updp,
                                              float* __restrict__ lossp, int nb) {
    __shared__ float sl[8 * SLICE_F];              // 46240 B
    __shared__ float lred[8];
    int tid = threadIdx.x;
    for (int i = tid; i < 8 * SLICE_F; i += 512) sl[i] = 0.f;
    __syncthreads();

    int lane = tid & 63;
    int w    = tid >> 6;
    int dq   = w & 3;
    int wg   = w >> 2;
    int sub  = lane >> 4;
    int l16  = lane & 15;
    float* slice = sl + w * SLICE_F;

    int ppc    = BT / (nb * 2);
    int p0     = (blockIdx.x * 2 + wg) * ppc;
    int nsteps = ppc / 4;

    float lsum = 0.f;
    uint4 lmv = *(const uint4*)(labm + p0);
    float f   = feat[(size_t)(p0 + sub) * DD + dq * 16 + l16];

    for (int s = 0; s < nsteps; ++s) {
        uint4 lv = lmv; float fc = f;
        if (s + 1 < nsteps) {
            int pn = p0 + (s + 1) * 4;
            lmv = *(const uint4*)(labm + pn);
            f   = feat[(size_t)(pn + sub) * DD + dq * 16 + l16];
        }
        unsigned a0 = lv.x & 0x7fffffffu, a1 = lv.y & 0x7fffffffu,
                 a2 = lv.z & 0x7fffffffu, a3 = lv.w & 0x7fffffffu;
        bool dup = (a0 == a1) | (a0 == a2) | (a0 == a3) |
                   (a1 == a2) | (a1 == a3) | (a2 == a3);   // wave-uniform
        unsigned lw = (sub & 2) ? ((sub & 1) ? lv.w : lv.z)
                                : ((sub & 1) ? lv.y : lv.x);
        float m = (float)(lw >> 31);
        int  la = (int)(lw & 0x7fffffffu);
        float c = m * fc;
        lsum = fmaf(c, fc, lsum);
        int a = la * 17 + l16;
        if (!dup) slice[a] += c;
        else      atomicAdd(&slice[a], c);
    }
    __syncthreads();

    float* myp = updp + (size_t)blockIdx.x * (NC * DD);
    for (int i = tid; i < NC * DD; i += 512) {
        int r = i >> 6, d = i & 63;
        int qq = d >> 4, d16 = d & 15;
        myp[i] = sl[qq * SLICE_F + r * 17 + d16] +
                 sl[(qq + 4) * SLICE_F + r * 17 + d16];
    }
#pragma unroll
    for (int off = 32; off; off >>= 1) lsum += __shfl_xor(lsum, off);
    if (lane == 0) lred[w] = lsum;
    __syncthreads();
    if (tid == 0) {
        float s = 0.f;
#pragma unroll
        for (int ww = 0; ww < 8; ++ww) s += lred[ww];
        lossp[blockIdx.x] = s;
    }
}

// ---------------------------------------------------------------------------
// Kernel 3: grid NC*4+1. Block (j,q) reduces F over nb partials for 16 dims,
// writes new centers, atomically accumulates 0.5*loss-piece into out[0].
// Last block does the same for Sfeat. out[0] was zeroed by k_amask.
// ---------------------------------------------------------------------------
__global__ __launch_bounds__(256) void k_reduce(const float* __restrict__ updp,
                                                const float* __restrict__ lossp,
                                                const float* __restrict__ centers,
                                                const int* __restrict__ counts,
                                                float* __restrict__ out, int nb) {
    __shared__ float sred[256];
    __shared__ float sr[4];
    int tid = threadIdx.x;
    int bid = blockIdx.x;
    if (bid < NC * 4) {
        int j = bid >> 2, q = bid & 3;
        int i = tid & 15;
        int c16 = tid >> 4;
        int per = nb >> 4;
        int col = j * DD + q * 16 + i;
        float s = 0.f;
        for (int b = c16 * per; b < (c16 + 1) * per; ++b)
            s += updp[(size_t)b * (NC * DD) + col];
        sred[tid] = s;
        __syncthreads();
        if (tid < 16) {
            float F = 0.f;
#pragma unroll
            for (int cc = 0; cc < 16; ++cc) F += sred[cc * 16 + i];
            float c   = centers[col];
            float cnt = (float)counts[j];
            float scale = ALPHA / (1.f + cnt);
            out[1 + col] = c - scale * (cnt * c - F);
            float lp = cnt * c * c - 2.f * c * F;
#pragma unroll
            for (int off = 8; off; off >>= 1) lp += __shfl_xor(lp, off);
            if (i == 0) atomicAdd(&out[0], 0.5f * lp);
        }
    } else {
        float s = 0.f;
        for (int t = tid; t < nb; t += 256) s += lossp[t];
#pragma unroll
        for (int off = 32; off; off >>= 1) s += __shfl_xor(s, off);
        int lane = tid & 63, wv = tid >> 6;
        if (lane == 0) sr[wv] = s;
        __syncthreads();
        if (tid == 0) atomicAdd(&out[0], 0.5f * (sr[0] + sr[1] + sr[2] + sr[3]));
    }
}

// ---------------------------------------------------------------------------
extern "C" void kernel_launch(void* const* d_in, const int* in_sizes, int n_in,
                              void* d_out, int out_size, void* d_ws, size_t ws_size,
                              hipStream_t stream) {
    const float* preds    = (const float*)d_in[0];
    const float* features = (const float*)d_in[1];
    const int*   labels   = (const int*)d_in[2];
    const float* centers  = (const float*)d_in[3];
    float* out = (float*)d_out;

    char* ws = (char*)d_ws;
    unsigned* labm = (unsigned*)ws;                             // BT words
    int* counts    = (int*)(ws + 4 * (size_t)BT);               // 85 ints
    size_t off0 = 4 * (size_t)BT + 512;

    int nb = 768;
    while (nb > 16 && off0 + (size_t)nb * 4 + 512 +
                      (size_t)nb * NC * DD * 4 > ws_size)
        nb >>= 1;
    float* lossp = (float*)(ws + off0);                         // nb floats
    float* updp  = (float*)(ws + off0 + (size_t)nb * 4 + 512);

    hipMemsetAsync(counts, 0, NC * sizeof(int), stream);
    k_amask<<<BB, 512, 0, stream>>>((const float4*)preds, labels, labm,
                                    counts, out);
    k_main<<<nb, 512, 0, stream>>>(features, labm, updp, lossp, nb);
    k_reduce<<<NC * 4 + 1, 256, 0, stream>>>(updp, lossp, centers, counts,
                                             out, nb);
}

// Round 7
// 88.529 us; speedup vs baseline: 1.6792x; 1.6792x over previous
//
#include <hip/hip_runtime.h>
#include <cstdint>

#define BB     4096
#define TT     96
#define NC     85
#define BLANKC 84
#define DD     64
#define ALPHA  0.05f
#define BT     (BB * TT)      // 393216
#define SLICE_F (NC * 17)     // 1445 floats per wave-private slice (pad 16->17)
#define NF4    (TT * NC / 4)  // 2040 float4 per batch row

// ---------------------------------------------------------------------------
// Kernel 1: fused argmax + CTC mask + per-block histogram. Block = one batch
// row (96 positions). Stage 96x85 floats via exactly-4 float4 loads/thread
// (uniform trip count -> unrolled, 4 loads in flight before LDS writes).
// Scan stride-85 (odd: conflict-free), thread (r,q) owns a column quarter,
// combine keeps lowest-col on ties. Mask uses in-block pls[t+1]. Histogram
// stays in LDS; per-block result written (unconditionally) to transposed
// hpartT[class][block] — NO global atomics anywhere.
// ---------------------------------------------------------------------------
template<int C0, int C1>
__device__ inline void scanR(const float* __restrict__ row, float& bv, int& bc) {
    bv = row[C0]; bc = C0;
#pragma unroll
    for (int c = C0 + 1; c < C1; ++c) {
        float v = row[c];
        if (v > bv) { bv = v; bc = c; }
    }
}

__global__ __launch_bounds__(512) void k_amask(const float4* __restrict__ p4,
                                               const int* __restrict__ labels,
                                               unsigned* __restrict__ labm,
                                               int* __restrict__ hpartT,
                                               float* __restrict__ out) {
    __shared__ float rows[TT * NC];                // 8160 floats, stride 85
    __shared__ float sv[4 * TT];
    __shared__ int   sc[4 * TT];
    __shared__ int   pls[TT];
    __shared__ int   h[NC];
    int tid = threadIdx.x;
    int b   = blockIdx.x;
    if (tid < NC) h[tid] = 0;
    if (b == 0 && tid == 480) out[0] = 0.f;

    // stage: exactly 4 float4 per thread; all loads issued before writes
    const float4* src = p4 + (size_t)b * NF4;
    float4* r4 = (float4*)rows;
    float4 v[4];
#pragma unroll
    for (int k = 0; k < 4; ++k)
        v[k] = src[min(tid + k * 512, NF4 - 1)];
#pragma unroll
    for (int k = 0; k < 4; ++k) {
        int i = tid + k * 512;
        if (i < NF4) r4[i] = v[k];
    }
    __syncthreads();

    // scan: thread = q*128 + r ; q wave-uniform
    int q = tid >> 7, r = tid & 127;
    if (r < TT) {
        const float* row = rows + r * NC;
        float bv; int bc;
        switch (q) {
            case 0:  scanR< 0, 22>(row, bv, bc); break;
            case 1:  scanR<22, 43>(row, bv, bc); break;
            case 2:  scanR<43, 64>(row, bv, bc); break;
            default: scanR<64, 85>(row, bv, bc); break;
        }
        sv[q * TT + r] = bv; sc[q * TT + r] = bc;
    }
    __syncthreads();
    if (tid < TT) {
        float bv = sv[tid]; int bc = sc[tid];
#pragma unroll
        for (int qq = 1; qq < 4; ++qq) {
            float v2 = sv[qq * TT + tid];
            int   c2 = sc[qq * TT + tid];
            if (v2 > bv) { bv = v2; bc = c2; }     // strict >: lower col wins ties
        }
        pls[tid] = bc;
    }
    __syncthreads();
    if (tid < TT) {
        int p = pls[tid];
        int m = (p != BLANKC) && (tid == TT - 1 || p != pls[tid + 1]);
        int lab = labels[b * TT + tid];
        labm[b * TT + tid] = (unsigned)lab | ((unsigned)m << 31);
        atomicAdd(&h[lab], m);                     // LDS only
    }
    __syncthreads();
    if (tid < NC) hpartT[tid * BB + b] = h[tid];   // unconditional, transposed
}

// ---------------------------------------------------------------------------
// Kernel 2: masked feature segment-sum. 8 waves/block; wave w owns dim-quad
// dq=w&3 with a PRIVATE slice [85][17]. Per step: one broadcast uint4 load of
// 4 packed label words; dup check = 6 wave-uniform compares; own label = 2
// selects. LDS ops/step: 1 ds_read + 1 ds_write (atomic fallback ~7%).
// ---------------------------------------------------------------------------
__global__ __launch_bounds__(512) void k_main(const float* __restrict__ feat,
                                              const unsigned* __restrict__ labm,
                                              float* __restrict__ updp,
                                              float* __restrict__ lossp, int nb) {
    __shared__ float sl[8 * SLICE_F];              // 46240 B
    __shared__ float lred[8];
    int tid = threadIdx.x;
    for (int i = tid; i < 8 * SLICE_F; i += 512) sl[i] = 0.f;
    __syncthreads();

    int lane = tid & 63;
    int w    = tid >> 6;
    int dq   = w & 3;
    int wg   = w >> 2;
    int sub  = lane >> 4;
    int l16  = lane & 15;
    float* slice = sl + w * SLICE_F;

    int ppc    = BT / (nb * 2);
    int p0     = (blockIdx.x * 2 + wg) * ppc;
    int nsteps = ppc / 4;

    float lsum = 0.f;
    uint4 lmv = *(const uint4*)(labm + p0);
    float f   = feat[(size_t)(p0 + sub) * DD + dq * 16 + l16];

    for (int s = 0; s < nsteps; ++s) {
        uint4 lv = lmv; float fc = f;
        if (s + 1 < nsteps) {
            int pn = p0 + (s + 1) * 4;
            lmv = *(const uint4*)(labm + pn);
            f   = feat[(size_t)(pn + sub) * DD + dq * 16 + l16];
        }
        unsigned a0 = lv.x & 0x7fffffffu, a1 = lv.y & 0x7fffffffu,
                 a2 = lv.z & 0x7fffffffu, a3 = lv.w & 0x7fffffffu;
        bool dup = (a0 == a1) | (a0 == a2) | (a0 == a3) |
                   (a1 == a2) | (a1 == a3) | (a2 == a3);   // wave-uniform
        unsigned lw = (sub & 2) ? ((sub & 1) ? lv.w : lv.z)
                                : ((sub & 1) ? lv.y : lv.x);
        float m = (float)(lw >> 31);
        int  la = (int)(lw & 0x7fffffffu);
        float c = m * fc;
        lsum = fmaf(c, fc, lsum);
        int a = la * 17 + l16;
        if (!dup) slice[a] += c;
        else      atomicAdd(&slice[a], c);
    }
    __syncthreads();

    float* myp = updp + (size_t)blockIdx.x * (NC * DD);
    for (int i = tid; i < NC * DD; i += 512) {
        int r = i >> 6, d = i & 63;
        int qq = d >> 4, d16 = d & 15;
        myp[i] = sl[qq * SLICE_F + r * 17 + d16] +
                 sl[(qq + 4) * SLICE_F + r * 17 + d16];
    }
#pragma unroll
    for (int off = 32; off; off >>= 1) lsum += __shfl_xor(lsum, off);
    if (lane == 0) lred[w] = lsum;
    __syncthreads();
    if (tid == 0) {
        float s = 0.f;
#pragma unroll
        for (int ww = 0; ww < 8; ++ww) s += lred[ww];
        lossp[blockIdx.x] = s;
    }
}

// ---------------------------------------------------------------------------
// Kernel 3: grid NC*4+1. Block (j,q): counts[j] = coalesced sum of
// hpartT[j][0..BB) (block reduction), then reduce F over nb partials for 16
// dims, write new centers, atomically add 0.5*loss-piece into out[0].
// Last block reduces Sfeat the same way. out[0] was zeroed by k_amask.
// ---------------------------------------------------------------------------
__global__ __launch_bounds__(256) void k_reduce(const float* __restrict__ updp,
                                                const float* __restrict__ lossp,
                                                const float* __restrict__ centers,
                                                const int* __restrict__ hpartT,
                                                float* __restrict__ out, int nb) {
    __shared__ float sred[256];
    __shared__ float sr[4];
    __shared__ int   scnt;
    int tid = threadIdx.x;
    int bid = blockIdx.x;
    if (bid < NC * 4) {
        int j = bid >> 2, q = bid & 3;
        // ---- counts[j]: coalesced 4096-int sum ----
        int cs = 0;
        for (int t = tid; t < BB; t += 256) cs += hpartT[j * BB + t];
#pragma unroll
        for (int off = 32; off; off >>= 1) cs += __shfl_xor(cs, off);
        int lane = tid & 63, wv = tid >> 6;
        if (lane == 0) ((int*)sred)[wv] = cs;
        __syncthreads();
        if (tid == 0)
            scnt = ((int*)sred)[0] + ((int*)sred)[1] +
                   ((int*)sred)[2] + ((int*)sred)[3];
        __syncthreads();
        float cnt = (float)scnt;
        // ---- F reduction over nb partials ----
        int i = tid & 15;
        int c16 = tid >> 4;
        int per = nb >> 4;
        int col = j * DD + q * 16 + i;
        float s = 0.f;
        for (int b = c16 * per; b < (c16 + 1) * per; ++b)
            s += updp[(size_t)b * (NC * DD) + col];
        sred[tid] = s;
        __syncthreads();
        if (tid < 16) {
            float F = 0.f;
#pragma unroll
            for (int cc = 0; cc < 16; ++cc) F += sred[cc * 16 + i];
            float c   = centers[col];
            float scale = ALPHA / (1.f + cnt);
            out[1 + col] = c - scale * (cnt * c - F);
            float lp = cnt * c * c - 2.f * c * F;
#pragma unroll
            for (int off = 8; off; off >>= 1) lp += __shfl_xor(lp, off);
            if (i == 0) atomicAdd(&out[0], 0.5f * lp);
        }
    } else {
        float s = 0.f;
        for (int t = tid; t < nb; t += 256) s += lossp[t];
#pragma unroll
        for (int off = 32; off; off >>= 1) s += __shfl_xor(s, off);
        int lane = tid & 63, wv = tid >> 6;
        if (lane == 0) sr[wv] = s;
        __syncthreads();
        if (tid == 0) atomicAdd(&out[0], 0.5f * (sr[0] + sr[1] + sr[2] + sr[3]));
    }
}

// ---------------------------------------------------------------------------
extern "C" void kernel_launch(void* const* d_in, const int* in_sizes, int n_in,
                              void* d_out, int out_size, void* d_ws, size_t ws_size,
                              hipStream_t stream) {
    const float* preds    = (const float*)d_in[0];
    const float* features = (const float*)d_in[1];
    const int*   labels   = (const int*)d_in[2];
    const float* centers  = (const float*)d_in[3];
    float* out = (float*)d_out;

    char* ws = (char*)d_ws;
    unsigned* labm = (unsigned*)ws;                             // BT words (1.5 MB)
    int* hpartT    = (int*)(ws + 4 * (size_t)BT);               // NC*BB ints (1.4 MB)
    size_t off0 = 4 * (size_t)BT + (size_t)NC * BB * 4 + 512;

    int nb = 768;
    while (nb > 16 && off0 + (size_t)nb * 4 + 512 +
                      (size_t)nb * NC * DD * 4 > ws_size)
        nb >>= 1;
    float* lossp = (float*)(ws + off0);                         // nb floats
    float* updp  = (float*)(ws + off0 + (size_t)nb * 4 + 512);

    k_amask<<<BB, 512, 0, stream>>>((const float4*)preds, labels, labm,
                                    hpartT, out);
    k_main<<<nb, 512, 0, stream>>>(features, labm, updp, lossp, nb);
    k_reduce<<<NC * 4 + 1, 256, 0, stream>>>(updp, lossp, centers, hpartT,
                                             out, nb);
}